// Round 14
// baseline (6431.193 us; speedup 1.0000x reference)
//
#include <hip/hip_runtime.h>
#include <hip/hip_bf16.h>
#include <math.h>

#define TT 64
#define HH 512
#define VV 30522
#define START_TOK 101
#define NTILE 477      // ceil(30522/64)
#define TPG 32         // timesteps per logits block

typedef __attribute__((ext_vector_type(8))) short short8v;
typedef __attribute__((ext_vector_type(4))) float f32x4;

__device__ inline short f2bf(float x) {
    union { float f; unsigned u; } v; v.f = x;
    unsigned r = v.u + 0x7FFFu + ((v.u >> 16) & 1u);   // RNE
    return (short)(r >> 16);
}
// packed (orderedFloat<<32 | ~col) key: atomicMax = max value, ties -> smaller col
__device__ inline unsigned long long packkey(float v, int col) {
    unsigned u = __float_as_uint(v);
    unsigned key = (u & 0x80000000u) ? ~u : (u | 0x80000000u);
    return ((unsigned long long)key << 32) | (unsigned)(0xFFFFFFFFu - (unsigned)col);
}
// unified LDS swizzle (involution, bits 4-6): slot ^= row ^ kseg.
__device__ __forceinline__ int swz(int base) {
    return base ^ ((((base >> 10) ^ (base >> 7)) & 7) << 4);
}

// ws layout (float units):
// h0[2][16384] @ 0 | h1[2][16384] @ 32768 | c0 @ 65536 | c1 @ 81920
// slots u64[64][32] @ 98304 (4096 floats, ends 102400) | wmax u32 @ 102400
// w_hi bf16[30522*512] @ 102432 (7813632 floats, ends 7916064)
// h1b16 bf16[64][32][512] @ 7916064 (524288 floats, ends 8440352) ~= 33.8 MB

__global__ void init_k(float* ws, const float* __restrict__ fused) {
    int i = blockIdx.x * blockDim.x + threadIdx.x;
    if (i < 16384) {
        float f = fused[i];
        ws[16384 + i] = f;            // h0 parity-1 (t=0 reads prev = buf1)
        ws[32768 + 16384 + i] = f;    // h1 parity-1
        ws[65536 + i] = 0.f;          // c0
        ws[81920 + i] = 0.f;          // c1
    }
    if (i < 4096) ((unsigned*)(ws + 98304))[i] = 0u;     // slots (reset every call!)
    if (i == 0) ((unsigned*)(ws + 102400))[0] = 0u;      // wmax (reset every call)
}

// fc_w fp32 -> bf16 (RNE, row-major) + global max column L2-norm
__global__ __launch_bounds__(256) void prep_k(const float* __restrict__ fc_w,
                                              short* __restrict__ w_hi,
                                              unsigned* __restrict__ wmax) {
    int r = blockIdx.x * 64 + (threadIdx.x >> 2);
    int seg = threadIdx.x & 3;
    if (r >= VV) return;
    const float* wp = fc_w + (size_t)r * HH + seg * 128;
    short* op = w_hi + (size_t)r * HH + seg * 128;
    float ss = 0.f;
#pragma unroll
    for (int c = 0; c < 16; ++c) {
        float4 x0 = *(const float4*)(wp + c * 8);
        float4 x1 = *(const float4*)(wp + c * 8 + 4);
        ss += x0.x*x0.x + x0.y*x0.y + x0.z*x0.z + x0.w*x0.w
            + x1.x*x1.x + x1.y*x1.y + x1.z*x1.z + x1.w*x1.w;
        short8v s;
        s[0]=f2bf(x0.x); s[1]=f2bf(x0.y); s[2]=f2bf(x0.z); s[3]=f2bf(x0.w);
        s[4]=f2bf(x1.x); s[5]=f2bf(x1.y); s[6]=f2bf(x1.z); s[7]=f2bf(x1.w);
        *(short8v*)(op + c * 8) = s;
    }
    ss += __shfl_xor(ss, 1); ss += __shfl_xor(ss, 2);
    if (seg == 0) atomicMax(wmax, __float_as_uint(sqrtf(ss)));
}

// One LSTM layer, one timestep. mode 0: x = emb[token], token resolved inline
// (teacher from target, generated from slots[t-1] atomicMax result — R1-proven
// encoding, read across dispatch boundary). mode 1: x = xsrc rows.
__global__ __launch_bounds__(256) void lstm_step(
    int t, int mode,
    const float* __restrict__ xsrc,
    const int* __restrict__ target,
    const int* __restrict__ tfm,
    const unsigned long long* __restrict__ slots,
    const float* __restrict__ hprev,
    float* __restrict__ hout,
    float* __restrict__ cstate,
    const float* __restrict__ w_ih,
    const float* __restrict__ w_hh,
    const float* __restrict__ b_ih,
    const float* __restrict__ b_hh,
    short* __restrict__ h1b16out)
{
    __shared__ float in_lds[32 * 258];
    __shared__ float red[32 * 64];
    __shared__ float gate[4 * 64];
    __shared__ int tok_lds[32];

    const int tid = threadIdx.x;
    const int j = tid >> 5, b = tid & 31;
    const int u0 = blockIdx.x * 2;

    if (mode == 0 && tid < 32) {
        int tok;
        if (t == 0) tok = START_TOK;
        else if (tfm[t - 1] > 0) tok = target[tid * TT + t];   // next_teacher[:,t-1]
        else tok = (int)(0xFFFFFFFFu - (unsigned)(slots[(t - 1) * 32 + tid] & 0xFFFFFFFFull));
        tok_lds[tid] = tok;
    }
    __syncthreads();

    float acc[8];
#pragma unroll
    for (int r = 0; r < 8; ++r) acc[r] = 0.f;
    int rowoff[8];
#pragma unroll
    for (int rl = 0; rl < 8; ++rl) {
        int gt = rl >> 1, ul = rl & 1;
        rowoff[rl] = (gt * 512 + u0 + ul) * 512;
    }

    for (int p = 0; p < 4; ++p) {
        const int koff = (p & 1) * 256;
        for (int i = tid; i < 32 * 128; i += 256) {
            int bb2 = i >> 7, k2 = (i & 127) * 2;
            const float* rp;
            if (p < 2) rp = (mode == 0) ? (xsrc + (size_t)tok_lds[bb2] * 512) : (xsrc + bb2 * 512);
            else       rp = hprev + bb2 * 512;
            float2 v = *(const float2*)(rp + koff + k2);
            *(float2*)&in_lds[bb2 * 258 + k2] = v;
        }
        __syncthreads();
        const float* wb = (p < 2) ? w_ih : w_hh;
#pragma unroll
        for (int m2 = 0; m2 < 8; ++m2) {
            int kl = j * 32 + m2 * 4;
            float2 x0 = *(const float2*)&in_lds[b * 258 + kl];
            float2 x1 = *(const float2*)&in_lds[b * 258 + kl + 2];
#pragma unroll
            for (int rl = 0; rl < 8; ++rl) {
                float4 w4 = *(const float4*)(wb + rowoff[rl] + koff + kl);
                acc[rl] += x0.x * w4.x + x0.y * w4.y + x1.x * w4.z + x1.y * w4.w;
            }
        }
        __syncthreads();
    }

#pragma unroll
    for (int rl = 0; rl < 8; ++rl) red[(b * 8 + rl) * 8 + j] = acc[rl];
    __syncthreads();

    {
        int b2 = tid >> 3, r2 = tid & 7;
        float s = 0.f;
#pragma unroll
        for (int jj = 0; jj < 8; ++jj) s += red[(b2 * 8 + r2) * 8 + jj];
        int gt = r2 >> 1, ul = r2 & 1;
        int rg = gt * 512 + u0 + ul;
        s += b_ih[rg] + b_hh[rg];
        gate[gt * 64 + ul * 32 + b2] = s;
    }
    __syncthreads();

    if (tid < 64) {
        int ul = tid >> 5, b3 = tid & 31;
        float gi = gate[0 * 64 + tid];
        float gf = gate[1 * 64 + tid];
        float gg = gate[2 * 64 + tid];
        float go = gate[3 * 64 + tid];
        float si = 1.f / (1.f + expf(-gi));
        float sf = 1.f / (1.f + expf(-gf));
        float so = 1.f / (1.f + expf(-go));
        float tg = tanhf(gg);
        int u = u0 + ul;
        float cold = cstate[b3 * 512 + u];
        float cn = sf * cold + si * tg;
        cstate[b3 * 512 + u] = cn;
        float h = so * tanhf(cn);
        hout[b3 * 512 + u] = h;
        if (h1b16out) h1b16out[b3 * 512 + u] = f2bf(h);
    }
}

// Candidate FC (non-TF steps): bf16 MFMA, per-block margin candidates, then
// in-block fp32 rescore of its own candidates + one atomicMax per row.
// Exactness: true global argmax col c* is within 2E of its block's bf16 max
// (E = xnorm*wmax*2^-8), so it is captured, rescored exactly in fp32, and its
// packkey wins the device-scope atomicMax (ties -> smaller col, = jnp.argmax).
__global__ __launch_bounds__(256) void fcarg(
    int t,
    const int* __restrict__ tfm,
    const float* __restrict__ h1,     // [32][512] fp32
    const short* __restrict__ w_hi,   // [30522][512] bf16 row-major
    const float* __restrict__ fc_w,   // fp32 (rescore)
    const float* __restrict__ fc_b,
    unsigned long long* __restrict__ slots,
    const unsigned* __restrict__ wmax)
{
    if (tfm[t] > 0) return;   // teacher-forced: argmax not needed

    __shared__ short a_sh[32 * 512];
    __shared__ float res_sh[32 * 68];
    __shared__ float xnorm_sh[32];
    __shared__ float wmax_sh;
    __shared__ int ccnt[32];
    __shared__ int clist[32][9];

    const int tid = threadIdx.x;
    const int blk = blockIdx.x;
    const float NEG_INF = -__builtin_inff();

    // Phase 1: h1 -> bf16 LDS (unified swizzle) + row norms
    {
        int row = tid >> 3, seg = tid & 7;
        const float* hp = h1 + row * 512 + seg * 64;
        float ss = 0.f;
#pragma unroll
        for (int c = 0; c < 8; ++c) {
            float4 x0 = *(const float4*)(hp + c * 8);
            float4 x1 = *(const float4*)(hp + c * 8 + 4);
            ss += x0.x*x0.x + x0.y*x0.y + x0.z*x0.z + x0.w*x0.w
                + x1.x*x1.x + x1.y*x1.y + x1.z*x1.z + x1.w*x1.w;
            short8v s;
            s[0]=f2bf(x0.x); s[1]=f2bf(x0.y); s[2]=f2bf(x0.z); s[3]=f2bf(x0.w);
            s[4]=f2bf(x1.x); s[5]=f2bf(x1.y); s[6]=f2bf(x1.z); s[7]=f2bf(x1.w);
            int kbase = seg * 64 + c * 8;
            *(short8v*)((char*)a_sh + swz(row * 1024 + kbase * 2)) = s;
        }
        ss += __shfl_xor(ss, 1); ss += __shfl_xor(ss, 2); ss += __shfl_xor(ss, 4);
        if (seg == 0) xnorm_sh[row] = sqrtf(ss);
        if (tid == 0) wmax_sh = __uint_as_float(*wmax);
    }
    __syncthreads();

    // Phase 2: MFMA
    const int w = tid >> 6, l = tid & 63;
    const int n0 = blk * 64 + w * 16;
    int bcol = n0 + (l & 15); if (bcol > VV - 1) bcol = VV - 1;
    const short* bp = w_hi + (size_t)bcol * HH + ((l >> 4) * 8);
    const int r0 = (l & 15), r1 = (l & 15) + 16;
    f32x4 acc0 = {0.f, 0.f, 0.f, 0.f}, acc1 = {0.f, 0.f, 0.f, 0.f};
#pragma unroll
    for (int kt = 0; kt < 16; ++kt) {
        int kb = (kt * 32 + (l >> 4) * 8) * 2;
        short8v bfrag = *(const short8v*)(bp + kt * 32);
        short8v a0 = *(const short8v*)((char*)a_sh + swz(r0 * 1024 + kb));
        short8v a1 = *(const short8v*)((char*)a_sh + swz(r1 * 1024 + kb));
        acc0 = __builtin_amdgcn_mfma_f32_16x16x32_bf16(a0, bfrag, acc0, 0, 0, 0);
        acc1 = __builtin_amdgcn_mfma_f32_16x16x32_bf16(a1, bfrag, acc1, 0, 0, 0);
    }

    // Phase 3: bias + res LDS
    {
        float bias = fc_b[bcol];
        bool oob = (n0 + (l & 15)) >= VV;
        int cl = w * 16 + (l & 15);
#pragma unroll
        for (int r = 0; r < 4; ++r) {
            int m = (l >> 4) * 4 + r;
            res_sh[m * 68 + cl]        = oob ? NEG_INF : acc0[r] + bias;
            res_sh[(m + 16) * 68 + cl] = oob ? NEG_INF : acc1[r] + bias;
        }
    }
    __syncthreads();

    // Phase 4: per-row block top + margin candidate list (in LDS)
    {
        int row = tid >> 3, sub = tid & 7;
        float bv = NEG_INF; int bc = 0x7FFFFFFF;
        for (int c = 0; c < 8; ++c) {
            float v = res_sh[row * 68 + sub * 8 + c];
            if (v > bv) { bv = v; bc = blk * 64 + sub * 8 + c; }
        }
#pragma unroll
        for (int d = 1; d < 8; d <<= 1) {
            float ov = __shfl_xor(bv, d);
            int oc = __shfl_xor(bc, d);
            if (ov > bv || (ov == bv && oc < bc)) { bv = ov; bc = oc; }
        }
        if (sub == 0) { clist[row][0] = bc; ccnt[row] = 1; }
        __syncthreads();
        float cthr = bv - xnorm_sh[row] * wmax_sh * (1.0f / 128.0f);   // bv - 2E
        for (int c = 0; c < 8; ++c) {
            float v = res_sh[row * 68 + sub * 8 + c];
            int col = blk * 64 + sub * 8 + c;
            if (v >= cthr && col != bc) {
                int idx = atomicAdd(&ccnt[row], 1);
                if (idx < 9) clist[row][idx] = col;
            }
        }
    }
    __syncthreads();

    // Phase 5: fp32 rescore of this block's candidates; one atomicMax per row.
    {
        int wv = tid >> 6, ln = tid & 63;
        for (int r2 = wv * 8; r2 < wv * 8 + 8; ++r2) {
            int nc = ccnt[r2]; if (nc > 9) nc = 9;
            float bv = NEG_INF; int bc2 = 0x7FFFFFFF;
            for (int jc = 0; jc < nc; ++jc) {
                int col = clist[r2][jc];
                const float* wp = fc_w + (size_t)col * HH + ln * 8;
                const float* xp = h1 + (size_t)r2 * 512 + ln * 8;
                float4 a0 = *(const float4*)wp, a1 = *(const float4*)(wp + 4);
                float4 b0 = *(const float4*)xp, b1 = *(const float4*)(xp + 4);
                float s = a0.x*b0.x + a0.y*b0.y + a0.z*b0.z + a0.w*b0.w
                        + a1.x*b1.x + a1.y*b1.y + a1.z*b1.z + a1.w*b1.w;
#pragma unroll
                for (int d = 1; d < 64; d <<= 1) s += __shfl_xor(s, d);
                s += fc_b[col];
                if (s > bv || (s == bv && col < bc2)) { bv = s; bc2 = col; }
            }
            if (ln == 0) atomicMax(&slots[t * 32 + r2], packkey(bv, bc2));
        }
    }
}

// Batched logits GEMM: [2048 x 30522] = h1b16 x w_hi^T + fc_b.
// TPG=32 (w_hi read 2x), unified swizzle, res alias, NT stores. (R13-proven)
__global__ __launch_bounds__(256) void logits_all(
    const short* __restrict__ h1b16,   // [64][32][512] bf16
    const short* __restrict__ w_hi,    // [30522][512] bf16 row-major
    const float* __restrict__ fc_b,
    float* __restrict__ out)
{
    __shared__ short a_sh[32 * 512];
    float* res_sh = (float*)a_sh;      // alias; guarded by barriers
    const int tid = threadIdx.x;
    const int blk = blockIdx.x;        // col tile
    const int tg  = blockIdx.y;        // TT/TPG groups
    const float NEG_INF = -__builtin_inff();

    const int w = tid >> 6, l = tid & 63;
    const int n0 = blk * 64 + w * 16;
    int bcol = n0 + (l & 15); if (bcol > VV - 1) bcol = VV - 1;
    const bool oob = (n0 + (l & 15)) >= VV;
    const float bias = fc_b[bcol];
    const short* bp = w_hi + (size_t)bcol * HH + ((l >> 4) * 8);
    short8v bfr[16];
#pragma unroll
    for (int kt = 0; kt < 16; ++kt) bfr[kt] = *(const short8v*)(bp + kt * 32);

    const int r0 = (l & 15), r1 = (l & 15) + 16;
    const int srow = tid >> 3, sseg = tid & 7;

    for (int ts = 0; ts < TPG; ++ts) {
        const int t = tg * TPG + ts;
        const short* hp = h1b16 + t * 16384 + srow * 512 + sseg * 64;
#pragma unroll
        for (int c = 0; c < 8; ++c) {
            short8v v = *(const short8v*)(hp + c * 8);
            int kbase = sseg * 64 + c * 8;
            *(short8v*)((char*)a_sh + swz(srow * 1024 + kbase * 2)) = v;
        }
        __syncthreads();

        f32x4 acc0 = {0.f,0.f,0.f,0.f}, acc1 = {0.f,0.f,0.f,0.f};
#pragma unroll
        for (int kt = 0; kt < 16; ++kt) {
            int kb = (kt * 32 + (l >> 4) * 8) * 2;
            short8v a0 = *(const short8v*)((char*)a_sh + swz(r0 * 1024 + kb));
            short8v a1 = *(const short8v*)((char*)a_sh + swz(r1 * 1024 + kb));
            acc0 = __builtin_amdgcn_mfma_f32_16x16x32_bf16(a0, bfr[kt], acc0, 0, 0, 0);
            acc1 = __builtin_amdgcn_mfma_f32_16x16x32_bf16(a1, bfr[kt], acc1, 0, 0, 0);
        }
        __syncthreads();   // a_sh reads done before res alias writes
        {
            int cl = w * 16 + (l & 15);
#pragma unroll
            for (int r = 0; r < 4; ++r) {
                int m = (l >> 4) * 4 + r;
                res_sh[m * 68 + cl]        = oob ? NEG_INF : acc0[r] + bias;
                res_sh[(m + 16) * 68 + cl] = oob ? NEG_INF : acc1[r] + bias;
            }
        }
        __syncthreads();
        for (int i = tid; i < 32 * 64; i += 256) {
            int m = i >> 6, cl = i & 63;
            int col = blk * 64 + cl;
            if (col < VV)
                __builtin_nontemporal_store(res_sh[m * 68 + cl],
                                            &out[((size_t)m * TT + t) * VV + col]);
        }
        __syncthreads();   // res alias dead before next ts restages a_sh
    }
}

extern "C" void kernel_launch(void* const* d_in, const int* in_sizes, int n_in,
                              void* d_out, int out_size, void* d_ws, size_t ws_size,
                              hipStream_t stream) {
    const float* fused  = (const float*)d_in[0];
    const int*   target = (const int*)d_in[1];
    const int*   tfm    = (const int*)d_in[2];
    const float* emb    = (const float*)d_in[3];
    const float* w_ih0  = (const float*)d_in[4];
    const float* w_hh0  = (const float*)d_in[5];
    const float* b_ih0  = (const float*)d_in[6];
    const float* b_hh0  = (const float*)d_in[7];
    const float* w_ih1  = (const float*)d_in[8];
    const float* w_hh1  = (const float*)d_in[9];
    const float* b_ih1  = (const float*)d_in[10];
    const float* b_hh1  = (const float*)d_in[11];
    const float* fc_w   = (const float*)d_in[12];
    const float* fc_b   = (const float*)d_in[13];
    float* out = (float*)d_out;

    float* ws = (float*)d_ws;
    float* h0buf = ws;
    float* h1buf = ws + 32768;
    float* c0 = ws + 65536;
    float* c1 = ws + 81920;
    unsigned long long* slots = (unsigned long long*)(ws + 98304);
    unsigned* wmax = (unsigned*)(ws + 102400);
    short* w_hi = (short*)(ws + 102432);
    short* h1b16 = (short*)(ws + 7916064);

    init_k<<<64, 256, 0, stream>>>(ws, fused);
    prep_k<<<NTILE, 256, 0, stream>>>(fc_w, w_hi, wmax);

    for (int t = 0; t < TT; ++t) {
        const float* h0prev = h0buf + ((t + 1) & 1) * 16384;
        float*       h0cur  = h0buf + (t & 1) * 16384;
        const float* h1prev = h1buf + ((t + 1) & 1) * 16384;
        float*       h1cur  = h1buf + (t & 1) * 16384;

        lstm_step<<<256, 256, 0, stream>>>(t, 0, emb, target, tfm, slots,
                                           h0prev, h0cur, c0, w_ih0, w_hh0, b_ih0, b_hh0,
                                           nullptr);
        lstm_step<<<256, 256, 0, stream>>>(t, 1, h0cur, target, tfm, slots,
                                           h1prev, h1cur, c1, w_ih1, w_hh1, b_ih1, b_hh1,
                                           h1b16 + (size_t)t * 16384);
        if (t < TT - 1)
            fcarg<<<NTILE, 256, 0, stream>>>(t, tfm, h1cur, w_hi, fc_w, fc_b,
                                             slots, wmax);
    }
    logits_all<<<dim3(NTILE, TT / TPG), 256, 0, stream>>>(h1b16, w_hi, fc_b, out);
}

// Round 15
// 3513.816 us; speedup vs baseline: 1.8303x; 1.8303x over previous
//
#include <hip/hip_runtime.h>
#include <hip/hip_bf16.h>
#include <math.h>

#define TT 64
#define HH 512
#define VV 30522
#define START_TOK 101
#define NTILE 477      // ceil(30522/64)
#define KCAND 8
#define TPG 32         // timesteps per logits block

typedef __attribute__((ext_vector_type(8))) short short8v;
typedef __attribute__((ext_vector_type(4))) float f32x4;

__device__ inline short f2bf(float x) {
    union { float f; unsigned u; } v; v.f = x;
    unsigned r = v.u + 0x7FFFu + ((v.u >> 16) & 1u);   // RNE
    return (short)(r >> 16);
}
__device__ inline unsigned long long packkey(float v, int col) {
    unsigned u = __float_as_uint(v);
    unsigned key = (u & 0x80000000u) ? ~u : (u | 0x80000000u);
    return ((unsigned long long)key << 32) | (unsigned)col;
}
__device__ inline float keyval(unsigned long long k) {
    unsigned hi = (unsigned)(k >> 32);
    unsigned bits = (hi & 0x80000000u) ? (hi ^ 0x80000000u) : ~hi;
    return __uint_as_float(bits);
}
// unified LDS swizzle (involution, bits 4-6): slot ^= row ^ kseg.
__device__ __forceinline__ int swz(int base) {
    return base ^ ((((base >> 10) ^ (base >> 7)) & 7) << 4);
}

// ws layout (float units):
// h0[2][16384] @ 0 | h1[2][16384] @ 32768 | c0 @ 65536 | c1 @ 81920
// tokbuf int[64*32] @ 98304 | xnorm f32[32] @ 100352 | wmax u32 @ 100384
// cand u64[32*477*8] @ 100416 (244224 floats, ends 344640)
// w_hi bf16[30522*512] @ 344640 | h1b16 bf16[64][32][512] @ 8158272

__global__ void init_k(float* ws, const float* __restrict__ fused) {
    int i = blockIdx.x * blockDim.x + threadIdx.x;
    if (i < 16384) {
        float f = fused[i];
        ws[16384 + i] = f;            // h0 parity-1 (t=0 reads prev = buf1)
        ws[32768 + 16384 + i] = f;    // h1 parity-1
        ws[65536 + i] = 0.f;          // c0
        ws[81920 + i] = 0.f;          // c1
    }
    if (i == 0) ((unsigned*)(ws + 100384))[0] = 0u;      // wmax (reset every call)
}

// fc_w fp32 -> bf16 (RNE, row-major) + global max column L2-norm
__global__ __launch_bounds__(256) void prep_k(const float* __restrict__ fc_w,
                                              short* __restrict__ w_hi,
                                              unsigned* __restrict__ wmax) {
    int r = blockIdx.x * 64 + (threadIdx.x >> 2);
    int seg = threadIdx.x & 3;
    if (r >= VV) return;
    const float* wp = fc_w + (size_t)r * HH + seg * 128;
    short* op = w_hi + (size_t)r * HH + seg * 128;
    float ss = 0.f;
#pragma unroll
    for (int c = 0; c < 16; ++c) {
        float4 x0 = *(const float4*)(wp + c * 8);
        float4 x1 = *(const float4*)(wp + c * 8 + 4);
        ss += x0.x*x0.x + x0.y*x0.y + x0.z*x0.z + x0.w*x0.w
            + x1.x*x1.x + x1.y*x1.y + x1.z*x1.z + x1.w*x1.w;
        short8v s;
        s[0]=f2bf(x0.x); s[1]=f2bf(x0.y); s[2]=f2bf(x0.z); s[3]=f2bf(x0.w);
        s[4]=f2bf(x1.x); s[5]=f2bf(x1.y); s[6]=f2bf(x1.z); s[7]=f2bf(x1.w);
        *(short8v*)(op + c * 8) = s;
    }
    ss += __shfl_xor(ss, 1); ss += __shfl_xor(ss, 2);
    if (seg == 0) atomicMax(wmax, __float_as_uint(sqrtf(ss)));
}

// One LSTM layer, one timestep. Single-stage variant: x and h staged once
// into one LDS buffer (1 barrier), compute loops preserve the R2/R13
// per-thread k-order exactly -> bit-identical gates/h/c.
// mode 0: x = emb[tokbuf]; mode 1: x = xsrc rows.
__global__ __launch_bounds__(256) void lstm_step(
    int t, int mode,
    const float* __restrict__ xsrc,
    const int* __restrict__ tokbuf,
    const float* __restrict__ hprev,
    float* __restrict__ hout,
    float* __restrict__ cstate,
    const float* __restrict__ w_ih,
    const float* __restrict__ w_hh,
    const float* __restrict__ b_ih,
    const float* __restrict__ b_hh,
    short* __restrict__ h1b16out)
{
    __shared__ float in_lds[32 * 1026];   // [b][0..511]=x, [b][512..1023]=h
    __shared__ float red[32 * 64];
    __shared__ float gate[4 * 64];
    __shared__ int tok_lds[32];

    const int tid = threadIdx.x;
    const int j = tid >> 5, b = tid & 31;
    const int u0 = blockIdx.x * 2;

    if (mode == 0 && tid < 32)
        tok_lds[tid] = (t == 0) ? START_TOK : tokbuf[t * 32 + tid];
    __syncthreads();

    // stage x (32x512) and h (32x512), float4
    for (int i = tid; i < 32 * 128; i += 256) {
        int bb2 = i >> 7, k4 = (i & 127) * 4;
        const float* rp = (mode == 0) ? (xsrc + (size_t)tok_lds[bb2] * 512) : (xsrc + bb2 * 512);
        *(float4*)&in_lds[bb2 * 1026 + k4] = *(const float4*)(rp + k4);
    }
    for (int i = tid; i < 32 * 128; i += 256) {
        int bb2 = i >> 7, k4 = (i & 127) * 4;
        *(float4*)&in_lds[bb2 * 1026 + 512 + k4] = *(const float4*)(hprev + bb2 * 512 + k4);
    }
    __syncthreads();

    float acc[8];
#pragma unroll
    for (int r = 0; r < 8; ++r) acc[r] = 0.f;
    int rowoff[8];
#pragma unroll
    for (int rl = 0; rl < 8; ++rl) {
        int gt = rl >> 1, ul = rl & 1;
        rowoff[rl] = (gt * 512 + u0 + ul) * 512;
    }

#pragma unroll
    for (int p = 0; p < 4; ++p) {
        const int koff = (p & 1) * 256;
        const int lbase = (p < 2) ? 0 : 512;
        const float* wb = (p < 2) ? w_ih : w_hh;
#pragma unroll
        for (int m2 = 0; m2 < 8; ++m2) {
            int kl = j * 32 + m2 * 4;
            float2 x0 = *(const float2*)&in_lds[b * 1026 + lbase + koff + kl];
            float2 x1 = *(const float2*)&in_lds[b * 1026 + lbase + koff + kl + 2];
#pragma unroll
            for (int rl = 0; rl < 8; ++rl) {
                float4 w4 = *(const float4*)(wb + rowoff[rl] + koff + kl);
                acc[rl] += x0.x * w4.x + x0.y * w4.y + x1.x * w4.z + x1.y * w4.w;
            }
        }
    }

#pragma unroll
    for (int rl = 0; rl < 8; ++rl) red[(b * 8 + rl) * 8 + j] = acc[rl];
    __syncthreads();

    {
        int b2 = tid >> 3, r2 = tid & 7;
        float s = 0.f;
#pragma unroll
        for (int jj = 0; jj < 8; ++jj) s += red[(b2 * 8 + r2) * 8 + jj];
        int gt = r2 >> 1, ul = r2 & 1;
        int rg = gt * 512 + u0 + ul;
        s += b_ih[rg] + b_hh[rg];
        gate[gt * 64 + ul * 32 + b2] = s;
    }
    __syncthreads();

    if (tid < 64) {
        int ul = tid >> 5, b3 = tid & 31;
        float gi = gate[0 * 64 + tid];
        float gf = gate[1 * 64 + tid];
        float gg = gate[2 * 64 + tid];
        float go = gate[3 * 64 + tid];
        float si = 1.f / (1.f + expf(-gi));
        float sf = 1.f / (1.f + expf(-gf));
        float so = 1.f / (1.f + expf(-go));
        float tg = tanhf(gg);
        int u = u0 + ul;
        float cold = cstate[b3 * 512 + u];
        float cn = sf * cold + si * tg;
        cstate[b3 * 512 + u] = cn;
        float h = so * tanhf(cn);
        hout[b3 * 512 + u] = h;
        if (h1b16out) h1b16out[b3 * 512 + u] = f2bf(h);
    }
}

// Candidate-only FC (non-TF steps): bf16 MFMA + margin candidates. (R13-proven)
__global__ __launch_bounds__(256) void fcarg(
    int t,
    const int* __restrict__ tfm,
    const float* __restrict__ h1,     // [32][512] fp32
    const short* __restrict__ w_hi,   // [30522][512] bf16 row-major
    const float* __restrict__ fc_b,
    unsigned long long* __restrict__ cand,
    float* __restrict__ xnorm_g,
    const unsigned* __restrict__ wmax)
{
    if (tfm[t] > 0) return;   // teacher-forced: argmax not needed

    __shared__ short a_sh[32 * 512];
    __shared__ float res_sh[32 * 68];
    __shared__ float xnorm_sh[32];
    __shared__ float wmax_sh;
    __shared__ int cnt_sh[32];

    const int tid = threadIdx.x;
    const int blk = blockIdx.x;
    const float NEG_INF = -__builtin_inff();

    // Phase 1: h1 -> bf16 LDS (unified swizzle) + row norms
    {
        int row = tid >> 3, seg = tid & 7;
        const float* hp = h1 + row * 512 + seg * 64;
        float ss = 0.f;
#pragma unroll
        for (int c = 0; c < 8; ++c) {
            float4 x0 = *(const float4*)(hp + c * 8);
            float4 x1 = *(const float4*)(hp + c * 8 + 4);
            ss += x0.x*x0.x + x0.y*x0.y + x0.z*x0.z + x0.w*x0.w
                + x1.x*x1.x + x1.y*x1.y + x1.z*x1.z + x1.w*x1.w;
            short8v s;
            s[0]=f2bf(x0.x); s[1]=f2bf(x0.y); s[2]=f2bf(x0.z); s[3]=f2bf(x0.w);
            s[4]=f2bf(x1.x); s[5]=f2bf(x1.y); s[6]=f2bf(x1.z); s[7]=f2bf(x1.w);
            int kbase = seg * 64 + c * 8;
            *(short8v*)((char*)a_sh + swz(row * 1024 + kbase * 2)) = s;
        }
        ss += __shfl_xor(ss, 1); ss += __shfl_xor(ss, 2); ss += __shfl_xor(ss, 4);
        if (seg == 0) xnorm_sh[row] = sqrtf(ss);
        if (tid == 0) wmax_sh = __uint_as_float(*wmax);
    }
    __syncthreads();
    if (blk == 0 && tid < 32) xnorm_g[tid] = xnorm_sh[tid];

    // Phase 2: MFMA
    const int w = tid >> 6, l = tid & 63;
    const int n0 = blk * 64 + w * 16;
    int bcol = n0 + (l & 15); if (bcol > VV - 1) bcol = VV - 1;
    const short* bp = w_hi + (size_t)bcol * HH + ((l >> 4) * 8);
    const int r0 = (l & 15), r1 = (l & 15) + 16;
    f32x4 acc0 = {0.f, 0.f, 0.f, 0.f}, acc1 = {0.f, 0.f, 0.f, 0.f};
#pragma unroll
    for (int kt = 0; kt < 16; ++kt) {
        int kb = (kt * 32 + (l >> 4) * 8) * 2;
        short8v bfrag = *(const short8v*)(bp + kt * 32);
        short8v a0 = *(const short8v*)((char*)a_sh + swz(r0 * 1024 + kb));
        short8v a1 = *(const short8v*)((char*)a_sh + swz(r1 * 1024 + kb));
        acc0 = __builtin_amdgcn_mfma_f32_16x16x32_bf16(a0, bfrag, acc0, 0, 0, 0);
        acc1 = __builtin_amdgcn_mfma_f32_16x16x32_bf16(a1, bfrag, acc1, 0, 0, 0);
    }

    // Phase 3: bias + res LDS
    {
        float bias = fc_b[bcol];
        bool oob = (n0 + (l & 15)) >= VV;
        int cl = w * 16 + (l & 15);
#pragma unroll
        for (int r = 0; r < 4; ++r) {
            int m = (l >> 4) * 4 + r;
            res_sh[m * 68 + cl]        = oob ? NEG_INF : acc0[r] + bias;
            res_sh[(m + 16) * 68 + cl] = oob ? NEG_INF : acc1[r] + bias;
        }
    }
    __syncthreads();

    // Phase 4: per-row block top + margin candidates
    {
        int row = tid >> 3, sub = tid & 7;
        float bv = NEG_INF; int bc = 0x7FFFFFFF;
        for (int c = 0; c < 8; ++c) {
            float v = res_sh[row * 68 + sub * 8 + c];
            if (v > bv) { bv = v; bc = blk * 64 + sub * 8 + c; }
        }
#pragma unroll
        for (int d = 1; d < 8; d <<= 1) {
            float ov = __shfl_xor(bv, d);
            int oc = __shfl_xor(bc, d);
            if (ov > bv || (ov == bv && oc < bc)) { bv = ov; bc = oc; }
        }
        unsigned long long* slotp = cand + ((size_t)row * NTILE + blk) * KCAND;
        if (sub == 0) { slotp[0] = packkey(bv, bc); cnt_sh[row] = 1; }
        __syncthreads();
        float cthr = bv - xnorm_sh[row] * wmax_sh * (1.0f / 128.0f);
        for (int c = 0; c < 8; ++c) {
            float v = res_sh[row * 68 + sub * 8 + c];
            int col = blk * 64 + sub * 8 + c;
            if (v >= cthr && col != bc) {
                int idx = atomicAdd(&cnt_sh[row], 1);
                if (idx < KCAND) slotp[idx] = packkey(v, col);
            }
        }
        __syncthreads();
        if (sub == 0) {
            int n = cnt_sh[row]; if (n > KCAND) n = KCAND;
            for (int k = n; k < KCAND; ++k) slotp[k] = 0ull;
        }
    }
}

// Global candidate scan + exact fp32 rescore -> token for step t+1 (R2-proven;
// reads cand across the dispatch boundary — XCD-coherence safe per G16).
__global__ __launch_bounds__(256) void argmax_k(
    int t,
    const int* __restrict__ target,
    const int* __restrict__ tfm,
    const unsigned long long* __restrict__ cand,
    const float* __restrict__ h1,
    const float* __restrict__ fc_w,
    const float* __restrict__ fc_b,
    const float* __restrict__ xnorm,
    const unsigned* __restrict__ wmax,
    int* __restrict__ tokbuf)
{
    const int r = blockIdx.x, tid = threadIdx.x;
    if (tfm[t] > 0) {
        if (tid == 0) tokbuf[(t + 1) * 32 + r] = target[r * TT + t + 1];
        return;
    }
    __shared__ unsigned long long red[256];
    __shared__ int list[32];
    __shared__ int lcnt;
    const int n = NTILE * KCAND;
    const unsigned long long* cp = cand + (size_t)r * n;

    unsigned long long m = 0ull;
    for (int i = tid; i < n; i += 256) { unsigned long long k = cp[i]; m = (k > m) ? k : m; }
    red[tid] = m; __syncthreads();
    for (int s = 128; s > 0; s >>= 1) {
        if (tid < s) { unsigned long long o = red[tid + s]; if (o > red[tid]) red[tid] = o; }
        __syncthreads();
    }
    float Mv = keyval(red[0]);
    float thr = Mv - xnorm[r] * __uint_as_float(*wmax) * (1.0f / 128.0f);
    if (tid == 0) lcnt = 0;
    __syncthreads();
    for (int i = tid; i < n; i += 256) {
        unsigned long long k = cp[i];
        if (!k) continue;
        float v = keyval(k);
        if (v >= thr) {
            int idx = atomicAdd(&lcnt, 1);
            if (idx < 32) list[idx] = (int)(k & 0xFFFFFFFFull);
        }
    }
    __syncthreads();
    int nc = lcnt < 32 ? lcnt : 32;

    if (tid < 64) {
        float bv = -__builtin_inff(); int bc = 0x7FFFFFFF;
        for (int jc = 0; jc < nc; ++jc) {
            int col = list[jc];
            const float* wp = fc_w + (size_t)col * HH + tid * 8;
            const float* xp = h1 + r * 512 + tid * 8;
            float4 a0 = *(const float4*)wp, a1 = *(const float4*)(wp + 4);
            float4 b0 = *(const float4*)xp, b1 = *(const float4*)(xp + 4);
            float s = a0.x*b0.x + a0.y*b0.y + a0.z*b0.z + a0.w*b0.w
                    + a1.x*b1.x + a1.y*b1.y + a1.z*b1.z + a1.w*b1.w;
#pragma unroll
            for (int d = 1; d < 64; d <<= 1) s += __shfl_xor(s, d);
            s += fc_b[col];
            if (s > bv || (s == bv && col < bc)) { bv = s; bc = col; }
        }
        if (tid == 0) tokbuf[(t + 1) * 32 + r] = bc;
    }
}

// Batched logits GEMM: [2048 x 30522] = h1b16 x w_hi^T + fc_b. (R13-proven)
__global__ __launch_bounds__(256) void logits_all(
    const short* __restrict__ h1b16,   // [64][32][512] bf16
    const short* __restrict__ w_hi,    // [30522][512] bf16 row-major
    const float* __restrict__ fc_b,
    float* __restrict__ out)
{
    __shared__ short a_sh[32 * 512];
    float* res_sh = (float*)a_sh;      // alias; guarded by barriers
    const int tid = threadIdx.x;
    const int blk = blockIdx.x;        // col tile
    const int tg  = blockIdx.y;        // TT/TPG groups
    const float NEG_INF = -__builtin_inff();

    const int w = tid >> 6, l = tid & 63;
    const int n0 = blk * 64 + w * 16;
    int bcol = n0 + (l & 15); if (bcol > VV - 1) bcol = VV - 1;
    const bool oob = (n0 + (l & 15)) >= VV;
    const float bias = fc_b[bcol];
    const short* bp = w_hi + (size_t)bcol * HH + ((l >> 4) * 8);
    short8v bfr[16];
#pragma unroll
    for (int kt = 0; kt < 16; ++kt) bfr[kt] = *(const short8v*)(bp + kt * 32);

    const int r0 = (l & 15), r1 = (l & 15) + 16;
    const int srow = tid >> 3, sseg = tid & 7;

    for (int ts = 0; ts < TPG; ++ts) {
        const int t = tg * TPG + ts;
        const short* hp = h1b16 + t * 16384 + srow * 512 + sseg * 64;
#pragma unroll
        for (int c = 0; c < 8; ++c) {
            short8v v = *(const short8v*)(hp + c * 8);
            int kbase = sseg * 64 + c * 8;
            *(short8v*)((char*)a_sh + swz(srow * 1024 + kbase * 2)) = v;
        }
        __syncthreads();

        f32x4 acc0 = {0.f,0.f,0.f,0.f}, acc1 = {0.f,0.f,0.f,0.f};
#pragma unroll
        for (int kt = 0; kt < 16; ++kt) {
            int kb = (kt * 32 + (l >> 4) * 8) * 2;
            short8v a0 = *(const short8v*)((char*)a_sh + swz(r0 * 1024 + kb));
            short8v a1 = *(const short8v*)((char*)a_sh + swz(r1 * 1024 + kb));
            acc0 = __builtin_amdgcn_mfma_f32_16x16x32_bf16(a0, bfr[kt], acc0, 0, 0, 0);
            acc1 = __builtin_amdgcn_mfma_f32_16x16x32_bf16(a1, bfr[kt], acc1, 0, 0, 0);
        }
        __syncthreads();   // a_sh reads done before res alias writes
        {
            int cl = w * 16 + (l & 15);
#pragma unroll
            for (int r = 0; r < 4; ++r) {
                int m = (l >> 4) * 4 + r;
                res_sh[m * 68 + cl]        = oob ? NEG_INF : acc0[r] + bias;
                res_sh[(m + 16) * 68 + cl] = oob ? NEG_INF : acc1[r] + bias;
            }
        }
        __syncthreads();
        for (int i = tid; i < 32 * 64; i += 256) {
            int m = i >> 6, cl = i & 63;
            int col = blk * 64 + cl;
            if (col < VV)
                __builtin_nontemporal_store(res_sh[m * 68 + cl],
                                            &out[((size_t)m * TT + t) * VV + col]);
        }
        __syncthreads();   // res alias dead before next ts restages a_sh
    }
}

extern "C" void kernel_launch(void* const* d_in, const int* in_sizes, int n_in,
                              void* d_out, int out_size, void* d_ws, size_t ws_size,
                              hipStream_t stream) {
    const float* fused  = (const float*)d_in[0];
    const int*   target = (const int*)d_in[1];
    const int*   tfm    = (const int*)d_in[2];
    const float* emb    = (const float*)d_in[3];
    const float* w_ih0  = (const float*)d_in[4];
    const float* w_hh0  = (const float*)d_in[5];
    const float* b_ih0  = (const float*)d_in[6];
    const float* b_hh0  = (const float*)d_in[7];
    const float* w_ih1  = (const float*)d_in[8];
    const float* w_hh1  = (const float*)d_in[9];
    const float* b_ih1  = (const float*)d_in[10];
    const float* b_hh1  = (const float*)d_in[11];
    const float* fc_w   = (const float*)d_in[12];
    const float* fc_b   = (const float*)d_in[13];
    float* out = (float*)d_out;

    float* ws = (float*)d_ws;
    float* h0buf = ws;
    float* h1buf = ws + 32768;
    float* c0 = ws + 65536;
    float* c1 = ws + 81920;
    int* tokbuf = (int*)(ws + 98304);
    float* xnorm = ws + 100352;
    unsigned* wmax = (unsigned*)(ws + 100384);
    unsigned long long* cand = (unsigned long long*)(ws + 100416);
    short* w_hi = (short*)(ws + 344640);
    short* h1b16 = (short*)(ws + 8158272);

    init_k<<<64, 256, 0, stream>>>(ws, fused);
    prep_k<<<NTILE, 256, 0, stream>>>(fc_w, w_hi, wmax);

    for (int t = 0; t < TT; ++t) {
        const float* h0prev = h0buf + ((t + 1) & 1) * 16384;
        float*       h0cur  = h0buf + (t & 1) * 16384;
        const float* h1prev = h1buf + ((t + 1) & 1) * 16384;
        float*       h1cur  = h1buf + (t & 1) * 16384;

        lstm_step<<<256, 256, 0, stream>>>(t, 0, emb, tokbuf,
                                           h0prev, h0cur, c0, w_ih0, w_hh0, b_ih0, b_hh0,
                                           nullptr);
        lstm_step<<<256, 256, 0, stream>>>(t, 1, h0cur, tokbuf,
                                           h1prev, h1cur, c1, w_ih1, w_hh1, b_ih1, b_hh1,
                                           h1b16 + (size_t)t * 16384);
        if (t < TT - 1) {
            fcarg<<<NTILE, 256, 0, stream>>>(t, tfm, h1cur, w_hi, fc_b, cand, xnorm, wmax);
            argmax_k<<<32, 256, 0, stream>>>(t, target, tfm, cand, h1cur, fc_w, fc_b,
                                             xnorm, wmax, tokbuf);
        }
    }
    logits_all<<<dim3(NTILE, TT / TPG), 256, 0, stream>>>(h1b16, w_hi, fc_b, out);
}

// Round 16
// 3411.936 us; speedup vs baseline: 1.8849x; 1.0299x over previous
//
#include <hip/hip_runtime.h>
#include <hip/hip_bf16.h>
#include <math.h>

#define TT 64
#define HH 512
#define VV 30522
#define START_TOK 101
#define NTILE 477      // ceil(30522/64)
#define KCAND 8
#define TPG 16         // timesteps per logits block

typedef __attribute__((ext_vector_type(8))) short short8v;
typedef __attribute__((ext_vector_type(4))) float f32x4;

__device__ inline short f2bf(float x) {
    union { float f; unsigned u; } v; v.f = x;
    unsigned r = v.u + 0x7FFFu + ((v.u >> 16) & 1u);   // RNE
    return (short)(r >> 16);
}
__device__ inline float bf2f(short s) {
    return __uint_as_float(((unsigned)(unsigned short)s) << 16);
}
__device__ inline unsigned long long packkey(float v, int col) {
    unsigned u = __float_as_uint(v);
    unsigned key = (u & 0x80000000u) ? ~u : (u | 0x80000000u);
    return ((unsigned long long)key << 32) | (unsigned)col;
}
__device__ inline float keyval(unsigned long long k) {
    unsigned hi = (unsigned)(k >> 32);
    unsigned bits = (hi & 0x80000000u) ? (hi ^ 0x80000000u) : ~hi;
    return __uint_as_float(bits);
}
// unified LDS swizzle (involution, bits 4-6): slot ^= row ^ kseg.
__device__ __forceinline__ int swz(int base) {
    return base ^ ((((base >> 10) ^ (base >> 7)) & 7) << 4);
}

// ws layout (float units):
// h0[2][16384] @ 0 | h1[2][16384] @ 32768 | c0 @ 65536 | c1 @ 81920
// tokbuf int[64*32] @ 98304 | xnorm f32[32] @ 100352 | wmax u32 @ 100384
// cand u64[32*477*8] @ 100416 (244224 floats, ends 344640)
// w_hi bf16[30522*512] @ 344640 | h1b16 bf16[64][32][512] @ 8158272

__global__ void init_k(float* ws, const float* __restrict__ fused) {
    int i = blockIdx.x * blockDim.x + threadIdx.x;
    if (i < 16384) {
        float f = fused[i];
        ws[16384 + i] = f;            // h0 parity-1 (t=0 reads prev = buf1)
        ws[32768 + 16384 + i] = f;    // h1 parity-1
        ws[65536 + i] = 0.f;          // c0
        ws[81920 + i] = 0.f;          // c1
    }
    if (i == 0) ((unsigned*)(ws + 100384))[0] = 0u;      // wmax (reset every call)
}

// fc_w fp32 -> bf16 (RNE, row-major) + global max column L2-norm
__global__ __launch_bounds__(256) void prep_k(const float* __restrict__ fc_w,
                                              short* __restrict__ w_hi,
                                              unsigned* __restrict__ wmax) {
    int r = blockIdx.x * 64 + (threadIdx.x >> 2);
    int seg = threadIdx.x & 3;
    if (r >= VV) return;
    const float* wp = fc_w + (size_t)r * HH + seg * 128;
    short* op = w_hi + (size_t)r * HH + seg * 128;
    float ss = 0.f;
#pragma unroll
    for (int c = 0; c < 16; ++c) {
        float4 x0 = *(const float4*)(wp + c * 8);
        float4 x1 = *(const float4*)(wp + c * 8 + 4);
        ss += x0.x*x0.x + x0.y*x0.y + x0.z*x0.z + x0.w*x0.w
            + x1.x*x1.x + x1.y*x1.y + x1.z*x1.z + x1.w*x1.w;
        short8v s;
        s[0]=f2bf(x0.x); s[1]=f2bf(x0.y); s[2]=f2bf(x0.z); s[3]=f2bf(x0.w);
        s[4]=f2bf(x1.x); s[5]=f2bf(x1.y); s[6]=f2bf(x1.z); s[7]=f2bf(x1.w);
        *(short8v*)(op + c * 8) = s;
    }
    ss += __shfl_xor(ss, 1); ss += __shfl_xor(ss, 2);
    if (seg == 0) atomicMax(wmax, __float_as_uint(sqrtf(ss)));
}

// One LSTM layer, one timestep. Single-stage (R15-proven): x and h staged once,
// 1 stage barrier, compute preserves R2 per-thread k-order -> bit-identical.
__global__ __launch_bounds__(256) void lstm_step(
    int t, int mode,
    const float* __restrict__ xsrc,
    const int* __restrict__ tokbuf,
    const float* __restrict__ hprev,
    float* __restrict__ hout,
    float* __restrict__ cstate,
    const float* __restrict__ w_ih,
    const float* __restrict__ w_hh,
    const float* __restrict__ b_ih,
    const float* __restrict__ b_hh,
    short* __restrict__ h1b16out)
{
    __shared__ float in_lds[32 * 1026];   // [b][0..511]=x, [b][512..1023]=h
    __shared__ float red[32 * 64];
    __shared__ float gate[4 * 64];
    __shared__ int tok_lds[32];

    const int tid = threadIdx.x;
    const int j = tid >> 5, b = tid & 31;
    const int u0 = blockIdx.x * 2;

    if (mode == 0 && tid < 32)
        tok_lds[tid] = (t == 0) ? START_TOK : tokbuf[t * 32 + tid];
    __syncthreads();

    for (int i = tid; i < 32 * 128; i += 256) {
        int bb2 = i >> 7, k4 = (i & 127) * 4;
        const float* rp = (mode == 0) ? (xsrc + (size_t)tok_lds[bb2] * 512) : (xsrc + bb2 * 512);
        *(float4*)&in_lds[bb2 * 1026 + k4] = *(const float4*)(rp + k4);
    }
    for (int i = tid; i < 32 * 128; i += 256) {
        int bb2 = i >> 7, k4 = (i & 127) * 4;
        *(float4*)&in_lds[bb2 * 1026 + 512 + k4] = *(const float4*)(hprev + bb2 * 512 + k4);
    }
    __syncthreads();

    float acc[8];
#pragma unroll
    for (int r = 0; r < 8; ++r) acc[r] = 0.f;
    int rowoff[8];
#pragma unroll
    for (int rl = 0; rl < 8; ++rl) {
        int gt = rl >> 1, ul = rl & 1;
        rowoff[rl] = (gt * 512 + u0 + ul) * 512;
    }

#pragma unroll
    for (int p = 0; p < 4; ++p) {
        const int koff = (p & 1) * 256;
        const int lbase = (p < 2) ? 0 : 512;
        const float* wb = (p < 2) ? w_ih : w_hh;
#pragma unroll
        for (int m2 = 0; m2 < 8; ++m2) {
            int kl = j * 32 + m2 * 4;
            float2 x0 = *(const float2*)&in_lds[b * 1026 + lbase + koff + kl];
            float2 x1 = *(const float2*)&in_lds[b * 1026 + lbase + koff + kl + 2];
#pragma unroll
            for (int rl = 0; rl < 8; ++rl) {
                float4 w4 = *(const float4*)(wb + rowoff[rl] + koff + kl);
                acc[rl] += x0.x * w4.x + x0.y * w4.y + x1.x * w4.z + x1.y * w4.w;
            }
        }
    }

#pragma unroll
    for (int rl = 0; rl < 8; ++rl) red[(b * 8 + rl) * 8 + j] = acc[rl];
    __syncthreads();

    {
        int b2 = tid >> 3, r2 = tid & 7;
        float s = 0.f;
#pragma unroll
        for (int jj = 0; jj < 8; ++jj) s += red[(b2 * 8 + r2) * 8 + jj];
        int gt = r2 >> 1, ul = r2 & 1;
        int rg = gt * 512 + u0 + ul;
        s += b_ih[rg] + b_hh[rg];
        gate[gt * 64 + ul * 32 + b2] = s;
    }
    __syncthreads();

    if (tid < 64) {
        int ul = tid >> 5, b3 = tid & 31;
        float gi = gate[0 * 64 + tid];
        float gf = gate[1 * 64 + tid];
        float gg = gate[2 * 64 + tid];
        float go = gate[3 * 64 + tid];
        float si = 1.f / (1.f + expf(-gi));
        float sf = 1.f / (1.f + expf(-gf));
        float so = 1.f / (1.f + expf(-go));
        float tg = tanhf(gg);
        int u = u0 + ul;
        float cold = cstate[b3 * 512 + u];
        float cn = sf * cold + si * tg;
        cstate[b3 * 512 + u] = cn;
        float h = so * tanhf(cn);
        hout[b3 * 512 + u] = h;
        if (h1b16out) h1b16out[b3 * 512 + u] = f2bf(h);
    }
}

// Candidate-only FC (non-TF steps): stages A directly from h1b16 (bit-identical
// bf16 values; norms bf16-derived — margin headroom absorbs <0.5% shift).
__global__ __launch_bounds__(256) void fcarg(
    int t,
    const int* __restrict__ tfm,
    const short* __restrict__ h1b16_t,   // [32][512] bf16 (this step)
    const short* __restrict__ w_hi,      // [30522][512] bf16 row-major
    const float* __restrict__ fc_b,
    unsigned long long* __restrict__ cand,
    float* __restrict__ xnorm_g,
    const unsigned* __restrict__ wmax)
{
    if (tfm[t] > 0) return;   // teacher-forced: argmax not needed

    __shared__ short a_sh[32 * 512];
    __shared__ float res_sh[32 * 68];
    __shared__ float xnorm_sh[32];
    __shared__ float wmax_sh;
    __shared__ int cnt_sh[32];

    const int tid = threadIdx.x;
    const int blk = blockIdx.x;
    const float NEG_INF = -__builtin_inff();

    // Phase 1: h1b16 -> LDS (unified swizzle) + bf16-derived row norms
    {
        int row = tid >> 3, seg = tid & 7;
        const short* hp = h1b16_t + row * 512 + seg * 64;
        float ss = 0.f;
#pragma unroll
        for (int c = 0; c < 8; ++c) {
            short8v v = *(const short8v*)(hp + c * 8);
            int kbase = seg * 64 + c * 8;
            *(short8v*)((char*)a_sh + swz(row * 1024 + kbase * 2)) = v;
#pragma unroll
            for (int e = 0; e < 8; ++e) { float f = bf2f(v[e]); ss += f * f; }
        }
        ss += __shfl_xor(ss, 1); ss += __shfl_xor(ss, 2); ss += __shfl_xor(ss, 4);
        if (seg == 0) xnorm_sh[row] = sqrtf(ss);
        if (tid == 0) wmax_sh = __uint_as_float(*wmax);
    }
    __syncthreads();
    if (blk == 0 && tid < 32) xnorm_g[tid] = xnorm_sh[tid];

    // Phase 2: MFMA
    const int w = tid >> 6, l = tid & 63;
    const int n0 = blk * 64 + w * 16;
    int bcol = n0 + (l & 15); if (bcol > VV - 1) bcol = VV - 1;
    const short* bp = w_hi + (size_t)bcol * HH + ((l >> 4) * 8);
    const int r0 = (l & 15), r1 = (l & 15) + 16;
    f32x4 acc0 = {0.f, 0.f, 0.f, 0.f}, acc1 = {0.f, 0.f, 0.f, 0.f};
#pragma unroll
    for (int kt = 0; kt < 16; ++kt) {
        int kb = (kt * 32 + (l >> 4) * 8) * 2;
        short8v bfrag = *(const short8v*)(bp + kt * 32);
        short8v a0 = *(const short8v*)((char*)a_sh + swz(r0 * 1024 + kb));
        short8v a1 = *(const short8v*)((char*)a_sh + swz(r1 * 1024 + kb));
        acc0 = __builtin_amdgcn_mfma_f32_16x16x32_bf16(a0, bfrag, acc0, 0, 0, 0);
        acc1 = __builtin_amdgcn_mfma_f32_16x16x32_bf16(a1, bfrag, acc1, 0, 0, 0);
    }

    // Phase 3: bias + res LDS
    {
        float bias = fc_b[bcol];
        bool oob = (n0 + (l & 15)) >= VV;
        int cl = w * 16 + (l & 15);
#pragma unroll
        for (int r = 0; r < 4; ++r) {
            int m = (l >> 4) * 4 + r;
            res_sh[m * 68 + cl]        = oob ? NEG_INF : acc0[r] + bias;
            res_sh[(m + 16) * 68 + cl] = oob ? NEG_INF : acc1[r] + bias;
        }
    }
    __syncthreads();

    // Phase 4: per-row block top + margin candidates
    {
        int row = tid >> 3, sub = tid & 7;
        float bv = NEG_INF; int bc = 0x7FFFFFFF;
        for (int c = 0; c < 8; ++c) {
            float v = res_sh[row * 68 + sub * 8 + c];
            if (v > bv) { bv = v; bc = blk * 64 + sub * 8 + c; }
        }
#pragma unroll
        for (int d = 1; d < 8; d <<= 1) {
            float ov = __shfl_xor(bv, d);
            int oc = __shfl_xor(bc, d);
            if (ov > bv || (ov == bv && oc < bc)) { bv = ov; bc = oc; }
        }
        unsigned long long* slotp = cand + ((size_t)row * NTILE + blk) * KCAND;
        if (sub == 0) { slotp[0] = packkey(bv, bc); cnt_sh[row] = 1; }
        __syncthreads();
        float cthr = bv - xnorm_sh[row] * wmax_sh * (1.0f / 128.0f);
        for (int c = 0; c < 8; ++c) {
            float v = res_sh[row * 68 + sub * 8 + c];
            int col = blk * 64 + sub * 8 + c;
            if (v >= cthr && col != bc) {
                int idx = atomicAdd(&cnt_sh[row], 1);
                if (idx < KCAND) slotp[idx] = packkey(v, col);
            }
        }
        __syncthreads();
        if (sub == 0) {
            int n = cnt_sh[row]; if (n > KCAND) n = KCAND;
            for (int k = n; k < KCAND; ++k) slotp[k] = 0ull;
        }
    }
}

// Global candidate scan + exact fp32 rescore -> token for step t+1 (R2-proven;
// reads cand across the dispatch boundary — XCD-coherence safe per G16).
__global__ __launch_bounds__(256) void argmax_k(
    int t,
    const int* __restrict__ target,
    const int* __restrict__ tfm,
    const unsigned long long* __restrict__ cand,
    const float* __restrict__ h1,
    const float* __restrict__ fc_w,
    const float* __restrict__ fc_b,
    const float* __restrict__ xnorm,
    const unsigned* __restrict__ wmax,
    int* __restrict__ tokbuf)
{
    const int r = blockIdx.x, tid = threadIdx.x;
    if (tfm[t] > 0) {
        if (tid == 0) tokbuf[(t + 1) * 32 + r] = target[r * TT + t + 1];
        return;
    }
    __shared__ unsigned long long red[256];
    __shared__ int list[32];
    __shared__ int lcnt;
    const int n = NTILE * KCAND;
    const unsigned long long* cp = cand + (size_t)r * n;

    unsigned long long m = 0ull;
    for (int i = tid; i < n; i += 256) { unsigned long long k = cp[i]; m = (k > m) ? k : m; }
    red[tid] = m; __syncthreads();
    for (int s = 128; s > 0; s >>= 1) {
        if (tid < s) { unsigned long long o = red[tid + s]; if (o > red[tid]) red[tid] = o; }
        __syncthreads();
    }
    float Mv = keyval(red[0]);
    float thr = Mv - xnorm[r] * __uint_as_float(*wmax) * (1.0f / 128.0f);
    if (tid == 0) lcnt = 0;
    __syncthreads();
    for (int i = tid; i < n; i += 256) {
        unsigned long long k = cp[i];
        if (!k) continue;
        float v = keyval(k);
        if (v >= thr) {
            int idx = atomicAdd(&lcnt, 1);
            if (idx < 32) list[idx] = (int)(k & 0xFFFFFFFFull);
        }
    }
    __syncthreads();
    int nc = lcnt < 32 ? lcnt : 32;

    if (tid < 64) {
        float bv = -__builtin_inff(); int bc = 0x7FFFFFFF;
        for (int jc = 0; jc < nc; ++jc) {
            int col = list[jc];
            const float* wp = fc_w + (size_t)col * HH + tid * 8;
            const float* xp = h1 + r * 512 + tid * 8;
            float4 a0 = *(const float4*)wp, a1 = *(const float4*)(wp + 4);
            float4 b0 = *(const float4*)xp, b1 = *(const float4*)(xp + 4);
            float s = a0.x*b0.x + a0.y*b0.y + a0.z*b0.z + a0.w*b0.w
                    + a1.x*b1.x + a1.y*b1.y + a1.z*b1.z + a1.w*b1.w;
#pragma unroll
            for (int d = 1; d < 64; d <<= 1) s += __shfl_xor(s, d);
            s += fc_b[col];
            if (s > bv || (s == bv && col < bc)) { bv = s; bc = col; }
        }
        if (tid == 0) tokbuf[(t + 1) * 32 + r] = bc;
    }
}

// Batched logits GEMM: [2048 x 30522] = h1b16 x w_hi^T + fc_b.
// TPG=16 (4 t-groups: 1908 blocks for write-BW parallelism), unified swizzle,
// res alias, NT stores.
__global__ __launch_bounds__(256) void logits_all(
    const short* __restrict__ h1b16,   // [64][32][512] bf16
    const short* __restrict__ w_hi,    // [30522][512] bf16 row-major
    const float* __restrict__ fc_b,
    float* __restrict__ out)
{
    __shared__ short a_sh[32 * 512];
    float* res_sh = (float*)a_sh;      // alias; guarded by barriers
    const int tid = threadIdx.x;
    const int blk = blockIdx.x;        // col tile
    const int tg  = blockIdx.y;        // TT/TPG groups
    const float NEG_INF = -__builtin_inff();

    const int w = tid >> 6, l = tid & 63;
    const int n0 = blk * 64 + w * 16;
    int bcol = n0 + (l & 15); if (bcol > VV - 1) bcol = VV - 1;
    const bool oob = (n0 + (l & 15)) >= VV;
    const float bias = fc_b[bcol];
    const short* bp = w_hi + (size_t)bcol * HH + ((l >> 4) * 8);
    short8v bfr[16];
#pragma unroll
    for (int kt = 0; kt < 16; ++kt) bfr[kt] = *(const short8v*)(bp + kt * 32);

    const int r0 = (l & 15), r1 = (l & 15) + 16;
    const int srow = tid >> 3, sseg = tid & 7;

    for (int ts = 0; ts < TPG; ++ts) {
        const int t = tg * TPG + ts;
        const short* hp = h1b16 + t * 16384 + srow * 512 + sseg * 64;
#pragma unroll
        for (int c = 0; c < 8; ++c) {
            short8v v = *(const short8v*)(hp + c * 8);
            int kbase = sseg * 64 + c * 8;
            *(short8v*)((char*)a_sh + swz(srow * 1024 + kbase * 2)) = v;
        }
        __syncthreads();

        f32x4 acc0 = {0.f,0.f,0.f,0.f}, acc1 = {0.f,0.f,0.f,0.f};
#pragma unroll
        for (int kt = 0; kt < 16; ++kt) {
            int kb = (kt * 32 + (l >> 4) * 8) * 2;
            short8v a0 = *(const short8v*)((char*)a_sh + swz(r0 * 1024 + kb));
            short8v a1 = *(const short8v*)((char*)a_sh + swz(r1 * 1024 + kb));
            acc0 = __builtin_amdgcn_mfma_f32_16x16x32_bf16(a0, bfr[kt], acc0, 0, 0, 0);
            acc1 = __builtin_amdgcn_mfma_f32_16x16x32_bf16(a1, bfr[kt], acc1, 0, 0, 0);
        }
        __syncthreads();   // a_sh reads done before res alias writes
        {
            int cl = w * 16 + (l & 15);
#pragma unroll
            for (int r = 0; r < 4; ++r) {
                int m = (l >> 4) * 4 + r;
                res_sh[m * 68 + cl]        = oob ? NEG_INF : acc0[r] + bias;
                res_sh[(m + 16) * 68 + cl] = oob ? NEG_INF : acc1[r] + bias;
            }
        }
        __syncthreads();
        for (int i = tid; i < 32 * 64; i += 256) {
            int m = i >> 6, cl = i & 63;
            int col = blk * 64 + cl;
            if (col < VV)
                __builtin_nontemporal_store(res_sh[m * 68 + cl],
                                            &out[((size_t)m * TT + t) * VV + col]);
        }
        __syncthreads();   // res alias dead before next ts restages a_sh
    }
}

extern "C" void kernel_launch(void* const* d_in, const int* in_sizes, int n_in,
                              void* d_out, int out_size, void* d_ws, size_t ws_size,
                              hipStream_t stream) {
    const float* fused  = (const float*)d_in[0];
    const int*   target = (const int*)d_in[1];
    const int*   tfm    = (const int*)d_in[2];
    const float* emb    = (const float*)d_in[3];
    const float* w_ih0  = (const float*)d_in[4];
    const float* w_hh0  = (const float*)d_in[5];
    const float* b_ih0  = (const float*)d_in[6];
    const float* b_hh0  = (const float*)d_in[7];
    const float* w_ih1  = (const float*)d_in[8];
    const float* w_hh1  = (const float*)d_in[9];
    const float* b_ih1  = (const float*)d_in[10];
    const float* b_hh1  = (const float*)d_in[11];
    const float* fc_w   = (const float*)d_in[12];
    const float* fc_b   = (const float*)d_in[13];
    float* out = (float*)d_out;

    float* ws = (float*)d_ws;
    float* h0buf = ws;
    float* h1buf = ws + 32768;
    float* c0 = ws + 65536;
    float* c1 = ws + 81920;
    int* tokbuf = (int*)(ws + 98304);
    float* xnorm = ws + 100352;
    unsigned* wmax = (unsigned*)(ws + 100384);
    unsigned long long* cand = (unsigned long long*)(ws + 100416);
    short* w_hi = (short*)(ws + 344640);
    short* h1b16 = (short*)(ws + 8158272);

    init_k<<<64, 256, 0, stream>>>(ws, fused);
    prep_k<<<NTILE, 256, 0, stream>>>(fc_w, w_hi, wmax);

    for (int t = 0; t < TT; ++t) {
        const float* h0prev = h0buf + ((t + 1) & 1) * 16384;
        float*       h0cur  = h0buf + (t & 1) * 16384;
        const float* h1prev = h1buf + ((t + 1) & 1) * 16384;
        float*       h1cur  = h1buf + (t & 1) * 16384;

        lstm_step<<<256, 256, 0, stream>>>(t, 0, emb, tokbuf,
                                           h0prev, h0cur, c0, w_ih0, w_hh0, b_ih0, b_hh0,
                                           nullptr);
        lstm_step<<<256, 256, 0, stream>>>(t, 1, h0cur, tokbuf,
                                           h1prev, h1cur, c1, w_ih1, w_hh1, b_ih1, b_hh1,
                                           h1b16 + (size_t)t * 16384);
        if (t < TT - 1) {
            fcarg<<<NTILE, 256, 0, stream>>>(t, tfm, h1b16 + (size_t)t * 16384,
                                             w_hi, fc_b, cand, xnorm, wmax);
            argmax_k<<<32, 256, 0, stream>>>(t, target, tfm, cand, h1cur, fc_w, fc_b,
                                             xnorm, wmax, tokbuf);
        }
    }
    logits_all<<<dim3(NTILE, TT / TPG), 256, 0, stream>>>(h1b16, w_hi, fc_b, out);
}